// Round 1
// 167.744 us; speedup vs baseline: 1.0146x; 1.0146x over previous
//
#include <hip/hip_runtime.h>
#include <stdint.h>

typedef unsigned short u16;
typedef __bf16 bf16x8 __attribute__((ext_vector_type(8)));
typedef unsigned short u16x8 __attribute__((ext_vector_type(8)));
typedef unsigned short u16x4 __attribute__((ext_vector_type(4)));
typedef float f32x4 __attribute__((ext_vector_type(4)));
typedef uint32_t u32v4 __attribute__((ext_vector_type(4)));

#define LOG2E 1.4426950408889634f

typedef const __attribute__((address_space(1))) uint32_t as1_u32;
typedef __attribute__((address_space(3))) uint32_t as3_u32;

// float -> bf16 round-to-nearest-even
__device__ __forceinline__ u16 f2bf(float f) {
  union { float f; uint32_t i; } v; v.f = f;
  uint32_t r = (v.i + 0x7fffu + ((v.i >> 16) & 1u)) >> 16;
  return (u16)r;
}
__device__ __forceinline__ float bf2f(u16 u) {
  union { uint32_t i; float f; } v; v.i = ((uint32_t)u) << 16; return v.f;
}

// async global->LDS, 16B/lane. LDS dest = wave-uniform base; HW scatters
// lane i to base + i*16B (matches As/Bs row layout: row stride 64B).
__device__ __forceinline__ void gld_lds16(const void* g, void* l) {
  as1_u32* gp = (as1_u32*)((uintptr_t)g);
  as3_u32* lp = (as3_u32*)(uint32_t)(uintptr_t)(l);
  __builtin_amdgcn_global_load_lds(gp, lp, 16, 0, 0);
}

// ---------------------------------------------------------------------------
// Kernel 0: f32 -> bf16 convert.
// ---------------------------------------------------------------------------
__global__ __launch_bounds__(256) void f32_to_bf16(
    const float* __restrict__ x, const float* __restrict__ wq,
    const float* __restrict__ wk, const float* __restrict__ wv,
    u16* __restrict__ xc, u16* __restrict__ wqc,
    u16* __restrict__ wkc, u16* __restrict__ wvc) {
  const int z = blockIdx.y;
  const float* src = z == 0 ? x : (z == 1 ? wq : (z == 2 ? wk : wv));
  u16* dst = z == 0 ? xc : (z == 1 ? wqc : (z == 2 ? wkc : wvc));
  const int n = z == 0 ? (1 << 22) : (1 << 20);

  const int idx = (blockIdx.x * 256 + (int)threadIdx.x) * 8;
  if (idx >= n) return;
  const f32x4 a = *(const f32x4*)&src[idx];
  const f32x4 b = *(const f32x4*)&src[idx + 4];
  u16x8 o;
#pragma unroll
  for (int j = 0; j < 4; j++) { o[j] = f2bf(a[j]); o[j + 4] = f2bf(b[j]); }
  *(u16x8*)&dst[idx] = o;
}

// ---------------------------------------------------------------------------
// Kernel 1: QKV GEMM, 128x128 tile, BK=32, m97-style global_load_lds staging.
// Plain epilogue (no sincos: R9 lesson — keeps acc in regs, VGPR sane).
//  z=0/1: q/k = x @ W^T -> [4096][1024]
//  z=2  : vt = Wv @ x^T -> [1024][4096] (coalesced store)
// ---------------------------------------------------------------------------
__global__ __launch_bounds__(256) void qkv_gemm(
    const u16* __restrict__ xc, const u16* __restrict__ wqc,
    const u16* __restrict__ wkc, const u16* __restrict__ wvc,
    u16* __restrict__ qo, u16* __restrict__ ko, u16* __restrict__ vt) {
  __shared__ __align__(16) u16 As[128 * 32];
  __shared__ __align__(16) u16 Bs[128 * 32];

  const int tid = threadIdx.x;
  const int lane = tid & 63;
  const int w = tid >> 6;
  const int wm = w >> 1, wn = w & 1;
  const int quad = lane >> 4, m16 = lane & 15;
  const int which = blockIdx.z;

  const u16* __restrict__ Ap;
  const u16* __restrict__ Bp;
  int m0, n0;
  if (which == 2) {
    Ap = wvc; Bp = xc;
    m0 = blockIdx.x * 128;   // Wv rows (1024)
    n0 = blockIdx.y * 128;   // x rows (4096)
  } else {
    Ap = xc; Bp = which == 0 ? wqc : wkc;
    m0 = blockIdx.y * 128;   // x rows
    n0 = blockIdx.x * 128;   // W rows
  }

  const f32x4 z4 = {0.f, 0.f, 0.f, 0.f};
  f32x4 acc[4][4];
#pragma unroll
  for (int i = 0; i < 4; i++)
#pragma unroll
    for (int j = 0; j < 4; j++) acc[i][j] = z4;

  const int rowA = m0 + w * 32 + (lane >> 2);
  const int rowB = n0 + w * 32 + (lane >> 2);
  const int cch = (lane & 3) * 8;

  for (int k0 = 0; k0 < 1024; k0 += 32) {
    __syncthreads();  // prior MFMA reads of As/Bs complete
#pragma unroll
    for (int i = 0; i < 2; i++) {
      gld_lds16(&Ap[(size_t)(rowA + i * 16) * 1024 + k0 + cch],
                &As[(w * 32 + i * 16) * 32]);
      gld_lds16(&Bp[(size_t)(rowB + i * 16) * 1024 + k0 + cch],
                &Bs[(w * 32 + i * 16) * 32]);
    }
    __syncthreads();  // drains vmcnt (compiler-inserted) -> tiles ready

    bf16x8 af[4], bfr[4];
#pragma unroll
    for (int t = 0; t < 4; t++) {
      af[t]  = *(const bf16x8*)&As[(wm * 64 + t * 16 + m16) * 32 + quad * 8];
      bfr[t] = *(const bf16x8*)&Bs[(wn * 64 + t * 16 + m16) * 32 + quad * 8];
    }
#pragma unroll
    for (int mt = 0; mt < 4; mt++)
#pragma unroll
      for (int nt = 0; nt < 4; nt++)
        acc[mt][nt] = __builtin_amdgcn_mfma_f32_16x16x32_bf16(
            af[mt], bfr[nt], acc[mt][nt], 0, 0, 0);
  }

  // Epilogue. C/D layout: col(n)=lane&15, row(m)=quad*4+reg.
  if (which < 2) {
    u16* __restrict__ out = which == 0 ? qo : ko;
#pragma unroll
    for (int mt = 0; mt < 4; mt++) {
      const int row = m0 + wm * 64 + mt * 16 + quad * 4;
#pragma unroll
      for (int nt = 0; nt < 4; nt++) {
        const int n = n0 + wn * 64 + nt * 16 + m16;
        f32x4 a = acc[mt][nt];
#pragma unroll
        for (int r = 0; r < 4; r++)
          out[(size_t)(row + r) * 1024 + n] = f2bf(a[r]);
      }
    }
  } else {
#pragma unroll
    for (int mt = 0; mt < 4; mt++) {
      const int row = m0 + wm * 64 + mt * 16 + quad * 4;  // d index
#pragma unroll
      for (int nt = 0; nt < 4; nt++) {
        const int n = n0 + wn * 64 + nt * 16 + m16;       // x row
        f32x4 a = acc[mt][nt];
#pragma unroll
        for (int r = 0; r < 4; r++)
          vt[(size_t)(row + r) * 4096 + n] = f2bf(a[r]);
      }
    }
  }
}

// ---------------------------------------------------------------------------
// Kernel 2: standalone RoPE, in-place on q/k.
// ---------------------------------------------------------------------------
__global__ __launch_bounds__(256) void rope_inplace(u16* __restrict__ qb,
                                                    u16* __restrict__ kb) {
  u16* buf = blockIdx.y == 0 ? qb : kb;
  const int p = blockIdx.x * 256 + (int)threadIdx.x;
  const int nidx = p * 2;
  const int row = nidx >> 10;
  const int col = nidx & 1023;
  const int i = (col & 63) >> 1;
  const int t = row & 2047;
  const float theta = exp2f(-(float)i * 0.02595256324130752f);
  const float ang = (float)t * theta;
  float s, c;
  sincosf(ang, &s, &c);
  const float a0 = bf2f(buf[(size_t)row * 1024 + col]);
  const float a1 = bf2f(buf[(size_t)row * 1024 + col + 1]);
  buf[(size_t)row * 1024 + col]     = f2bf(a0 * c - a1 * s);
  buf[(size_t)row * 1024 + col + 1] = f2bf(a1 * c + a0 * s);
}

// ---------------------------------------------------------------------------
// Kernel 3: causal flash attention, NO-RESCALE softmax, IN-REGISTER P (T12).
// Swapped QK^T: S^T = mfma(K,Q) -> lane (m16,quad) holds S[key=nt*16+quad*4+r]
// [q=m16] for its q-column. P packed to bf16 in-register (v_cvt_pk_bf16_f32,
// RNE) and the PV A-fragment assembled with 4 v_permlane32_swap_b32 per tile
// (zero selects). Key order inside each 16-block is bit2<->bit3-permuted;
// the same permutation is folded into the Vs store so V fragment reads stay
// contiguous b128. l accumulated from the ROUNDED p (extracted from packed
// words) so rounding cancels in O/l. No Ps LDS buffer (27.6KB total).
// Pair-balanced grid (qt = x then 31-x), reg-prefetch K/V, 2 barriers/tile.
// ---------------------------------------------------------------------------
__global__ __launch_bounds__(256) void flash_attn(
    const u16* __restrict__ qg, const u16* __restrict__ kg,
    const u16* __restrict__ vt, float* __restrict__ out) {
  __shared__ __align__(16) u16 Qs[64 * 72];
  __shared__ __align__(16) u16 Ks[64 * 72];
  __shared__ __align__(16) u16 Vs[64 * 72];  // [d][kperm], kperm = swap23(key)

  const int tid = threadIdx.x, lane = tid & 63, w = tid >> 6;
  const int quad = lane >> 4, m16 = lane & 15;
  const int h = blockIdx.y, b = blockIdx.z;
  const size_t base = (size_t)b * 2048 * 1024 + (size_t)h * 64;
  const size_t vbase = (size_t)(h * 64) * 4096 + (size_t)b * 2048;
  const float SC = 0.03125f * LOG2E;

  const f32x4 z4 = {0.f, 0.f, 0.f, 0.f};
  const int srow = tid >> 2, sc = (tid & 3) * 16;

  for (int pass = 0; pass < 2; ++pass) {
    const int qt = pass == 0 ? (int)blockIdx.x : 31 - (int)blockIdx.x;
    const int q0 = qt * 64;

    __syncthreads();  // prior pass's LDS reads complete
    {
      const u16* src = &qg[base + (size_t)(q0 + srow) * 1024 + sc];
      *(u16x8*)&Qs[srow * 72 + sc] = *(const u16x8*)src;
      *(u16x8*)&Qs[srow * 72 + sc + 8] = *(const u16x8*)(src + 8);
    }
    u16x8 kr0, kr1, vr0, vr1;
    {
      const u16* ks = &kg[base + (size_t)srow * 1024 + sc];
      kr0 = *(const u16x8*)ks; kr1 = *(const u16x8*)(ks + 8);
      const u16* vs = &vt[vbase + (size_t)srow * 4096 + sc];
      vr0 = *(const u16x8*)vs; vr1 = *(const u16x8*)(vs + 8);
    }
    __syncthreads();
    const bf16x8 qf0 = *(const bf16x8*)&Qs[(w * 16 + m16) * 72 + quad * 8];
    const bf16x8 qf1 = *(const bf16x8*)&Qs[(w * 16 + m16) * 72 + 32 + quad * 8];

    float l_p = 0.f;  // per-lane partial denom for q = qcol
    f32x4 O[4];
#pragma unroll
    for (int d = 0; d < 4; d++) O[d] = z4;

    const int qrow0 = q0 + w * 16 + quad * 4;  // O store rows
    const int qcol  = q0 + w * 16 + m16;       // this lane's softmax q

    for (int kt = 0; kt <= qt; ++kt) {
      const int k0 = kt * 64;
      if (kt) __syncthreads();  // all waves done with prev Ks/Vs
      *(u16x8*)&Ks[srow * 72 + sc] = kr0;
      *(u16x8*)&Ks[srow * 72 + sc + 8] = kr1;
      {  // Vs store with key bit2<->bit3 swap: pos p <- actual key swap23(p)
        const u16x4* v0 = (const u16x4*)&vr0;
        const u16x4* v1 = (const u16x4*)&vr1;
        *(u16x4*)&Vs[srow * 72 + sc]      = v0[0];  // keys sc+0..3
        *(u16x4*)&Vs[srow * 72 + sc + 4]  = v1[0];  // keys sc+8..11
        *(u16x4*)&Vs[srow * 72 + sc + 8]  = v0[1];  // keys sc+4..7
        *(u16x4*)&Vs[srow * 72 + sc + 12] = v1[1];  // keys sc+12..15
      }
      __syncthreads();
      if (kt < qt) {  // prefetch next tile; overlaps MFMA + softmax
        const u16* ks = &kg[base + (size_t)(k0 + 64 + srow) * 1024 + sc];
        kr0 = *(const u16x8*)ks; kr1 = *(const u16x8*)(ks + 8);
        const u16* vs = &vt[vbase + (size_t)srow * 4096 + k0 + 64 + sc];
        vr0 = *(const u16x8*)vs; vr1 = *(const u16x8*)(vs + 8);
      }

      // S^T = K Q^T: S[nt] rows = key nt*16+quad*4+r, col = q (m16)
      f32x4 S[4];
#pragma unroll
      for (int nt = 0; nt < 4; nt++) {
        const bf16x8 kf0 = *(const bf16x8*)&Ks[(nt * 16 + m16) * 72 + quad * 8];
        const bf16x8 kf1 =
            *(const bf16x8*)&Ks[(nt * 16 + m16) * 72 + 32 + quad * 8];
        S[nt] = __builtin_amdgcn_mfma_f32_16x16x32_bf16(kf0, qf0, z4, 0, 0, 0);
        S[nt] = __builtin_amdgcn_mfma_f32_16x16x32_bf16(kf1, qf1, S[nt], 0, 0, 0);
      }

      // p = exp2(s*SC), masked on the diagonal tile; pack pairs to bf16 (RNE).
      const bool diag = (kt == qt);
      uint32_t W[8];  // W[2*nt+h] = pack(p[keys nt*16+quad*4+2h, +1])
#pragma unroll
      for (int nt = 0; nt < 4; nt++) {
        float p[4];
#pragma unroll
        for (int r = 0; r < 4; r++) {
          float e = exp2f(S[nt][r] * SC);
          const int key = k0 + nt * 16 + quad * 4 + r;
          if (diag && key > qcol) e = 0.f;
          p[r] = e;
        }
        uint32_t w0, w1;
        asm("v_cvt_pk_bf16_f32 %0, %1, %2" : "=v"(w0) : "v"(p[0]), "v"(p[1]));
        asm("v_cvt_pk_bf16_f32 %0, %1, %2" : "=v"(w1) : "v"(p[2]), "v"(p[3]));
        W[2 * nt] = w0; W[2 * nt + 1] = w1;
        union { uint32_t i; float f; } e0, e1, e2, e3;
        e0.i = w0 << 16; e1.i = w0 & 0xffff0000u;
        e2.i = w1 << 16; e3.i = w1 & 0xffff0000u;
        l_p += (e0.f + e1.f) + (e2.f + e3.f);  // l from ROUNDED p
      }

      // PV A-frags: (a',b') = permlane32_swap(a,b) gives
      //   a' = [a_lo | b_from(lane-32)], b' = [a_from(lane+32) | b_hi]
      // -> frag = [a'_h0, a'_h1, b'_h0, b'_h1] is correct for BOTH halves.
      uint32_t a0 = W[0], b0 = W[2], a1 = W[1], b1 = W[3];
      asm("v_permlane32_swap_b32 %0, %1" : "+v"(a0), "+v"(b0));
      asm("v_permlane32_swap_b32 %0, %1" : "+v"(a1), "+v"(b1));
      uint32_t a2 = W[4], b2 = W[6], a3 = W[5], b3 = W[7];
      asm("v_permlane32_swap_b32 %0, %1" : "+v"(a2), "+v"(b2));
      asm("v_permlane32_swap_b32 %0, %1" : "+v"(a3), "+v"(b3));
      union { u32v4 u; bf16x8 f; } P0, P1;
      P0.u = (u32v4){a0, a1, b0, b1};  // kperm keys 0..31
      P1.u = (u32v4){a2, a3, b2, b3};  // kperm keys 32..63

      // O += P V  (Vs already key-permuted to match the frag order)
#pragma unroll
      for (int dt = 0; dt < 4; dt++) {
        const bf16x8 vf0 = *(const bf16x8*)&Vs[(dt * 16 + m16) * 72 + quad * 8];
        const bf16x8 vf1 =
            *(const bf16x8*)&Vs[(dt * 16 + m16) * 72 + 32 + quad * 8];
        O[dt] = __builtin_amdgcn_mfma_f32_16x16x32_bf16(P0.f, vf0, O[dt], 0, 0, 0);
        O[dt] = __builtin_amdgcn_mfma_f32_16x16x32_bf16(P1.f, vf1, O[dt], 0, 0, 0);
      }
    }

    // cross-quad l reduction (4 lanes share each q), then fetch per-row inv
    l_p += __shfl_xor(l_p, 16);
    l_p += __shfl_xor(l_p, 32);
    float inv[4];
#pragma unroll
    for (int r = 0; r < 4; r++) inv[r] = 1.0f / __shfl(l_p, quad * 4 + r);

#pragma unroll
    for (int dt = 0; dt < 4; dt++)
#pragma unroll
      for (int r = 0; r < 4; r++)
        out[base + (size_t)(qrow0 + r) * 1024 + dt * 16 + m16] =
            O[dt][r] * inv[r];
  }
}

extern "C" void kernel_launch(void* const* d_in, const int* in_sizes, int n_in,
                              void* d_out, int out_size, void* d_ws, size_t ws_size,
                              hipStream_t stream) {
  const float* x  = (const float*)d_in[0];
  const float* Wq = (const float*)d_in[1];
  const float* Wk = (const float*)d_in[2];
  const float* Wv = (const float*)d_in[3];
  u16* qb  = (u16*)d_ws;                    // [4096][1024] bf16
  u16* kb  = qb  + (size_t)4096 * 1024;     // [4096][1024] bf16
  u16* vtw = kb  + (size_t)4096 * 1024;     // [1024][4096] bf16 (V^T)
  u16* xc  = vtw + (size_t)4096 * 1024;     // bf16 inputs
  u16* wqc = xc  + (size_t)4096 * 1024;
  u16* wkc = wqc + (size_t)1024 * 1024;
  u16* wvc = wkc + (size_t)1024 * 1024;

  f32_to_bf16<<<dim3(2048, 4), 256, 0, stream>>>(x, Wq, Wk, Wv,
                                                 xc, wqc, wkc, wvc);
  qkv_gemm<<<dim3(8, 32, 3), 256, 0, stream>>>(xc, wqc, wkc, wvc,
                                               qb, kb, vtw);
  rope_inplace<<<dim3(8192, 2), 256, 0, stream>>>(qb, kb);
  flash_attn<<<dim3(16, 16, 2), 256, 0, stream>>>(qb, kb, vtw, (float*)d_out);
}

// Round 2
// 166.769 us; speedup vs baseline: 1.0205x; 1.0058x over previous
//
#include <hip/hip_runtime.h>
#include <stdint.h>

typedef unsigned short u16;
typedef __bf16 bf16x8 __attribute__((ext_vector_type(8)));
typedef unsigned short u16x8 __attribute__((ext_vector_type(8)));
typedef unsigned short u16x4 __attribute__((ext_vector_type(4)));
typedef float f32x4 __attribute__((ext_vector_type(4)));
typedef uint32_t u32v4 __attribute__((ext_vector_type(4)));

#define LOG2E 1.4426950408889634f

typedef const __attribute__((address_space(1))) uint32_t as1_u32;
typedef __attribute__((address_space(3))) uint32_t as3_u32;

// float -> bf16 round-to-nearest-even
__device__ __forceinline__ u16 f2bf(float f) {
  union { float f; uint32_t i; } v; v.f = f;
  uint32_t r = (v.i + 0x7fffu + ((v.i >> 16) & 1u)) >> 16;
  return (u16)r;
}
__device__ __forceinline__ float bf2f(u16 u) {
  union { uint32_t i; float f; } v; v.i = ((uint32_t)u) << 16; return v.f;
}

// async global->LDS, 16B/lane. LDS dest = wave-uniform base; HW scatters
// lane i to base + i*16B (matches As/Bs row layout: row stride 64B).
__device__ __forceinline__ void gld_lds16(const void* g, void* l) {
  as1_u32* gp = (as1_u32*)((uintptr_t)g);
  as3_u32* lp = (as3_u32*)(uint32_t)(uintptr_t)(l);
  __builtin_amdgcn_global_load_lds(gp, lp, 16, 0, 0);
}

// ---------------------------------------------------------------------------
// Kernel 0: f32 -> bf16 convert.
// ---------------------------------------------------------------------------
__global__ __launch_bounds__(256) void f32_to_bf16(
    const float* __restrict__ x, const float* __restrict__ wq,
    const float* __restrict__ wk, const float* __restrict__ wv,
    u16* __restrict__ xc, u16* __restrict__ wqc,
    u16* __restrict__ wkc, u16* __restrict__ wvc) {
  const int z = blockIdx.y;
  const float* src = z == 0 ? x : (z == 1 ? wq : (z == 2 ? wk : wv));
  u16* dst = z == 0 ? xc : (z == 1 ? wqc : (z == 2 ? wkc : wvc));
  const int n = z == 0 ? (1 << 22) : (1 << 20);

  const int idx = (blockIdx.x * 256 + (int)threadIdx.x) * 8;
  if (idx >= n) return;
  const f32x4 a = *(const f32x4*)&src[idx];
  const f32x4 b = *(const f32x4*)&src[idx + 4];
  u16x8 o;
#pragma unroll
  for (int j = 0; j < 4; j++) { o[j] = f2bf(a[j]); o[j + 4] = f2bf(b[j]); }
  *(u16x8*)&dst[idx] = o;
}

// ---------------------------------------------------------------------------
// Kernel 1: QKV GEMM, 128x128 tile, BK=32, m97-style global_load_lds staging.
//  z=0/1: q/k = x @ W^T -> [4096][1024]
//  z=2  : vt = Wv @ x^T -> [1024][4096] (coalesced store)
// ---------------------------------------------------------------------------
__global__ __launch_bounds__(256) void qkv_gemm(
    const u16* __restrict__ xc, const u16* __restrict__ wqc,
    const u16* __restrict__ wkc, const u16* __restrict__ wvc,
    u16* __restrict__ qo, u16* __restrict__ ko, u16* __restrict__ vt) {
  __shared__ __align__(16) u16 As[128 * 32];
  __shared__ __align__(16) u16 Bs[128 * 32];

  const int tid = threadIdx.x;
  const int lane = tid & 63;
  const int w = tid >> 6;
  const int wm = w >> 1, wn = w & 1;
  const int quad = lane >> 4, m16 = lane & 15;
  const int which = blockIdx.z;

  const u16* __restrict__ Ap;
  const u16* __restrict__ Bp;
  int m0, n0;
  if (which == 2) {
    Ap = wvc; Bp = xc;
    m0 = blockIdx.x * 128;   // Wv rows (1024)
    n0 = blockIdx.y * 128;   // x rows (4096)
  } else {
    Ap = xc; Bp = which == 0 ? wqc : wkc;
    m0 = blockIdx.y * 128;   // x rows
    n0 = blockIdx.x * 128;   // W rows
  }

  const f32x4 z4 = {0.f, 0.f, 0.f, 0.f};
  f32x4 acc[4][4];
#pragma unroll
  for (int i = 0; i < 4; i++)
#pragma unroll
    for (int j = 0; j < 4; j++) acc[i][j] = z4;

  const int rowA = m0 + w * 32 + (lane >> 2);
  const int rowB = n0 + w * 32 + (lane >> 2);
  const int cch = (lane & 3) * 8;

  for (int k0 = 0; k0 < 1024; k0 += 32) {
    __syncthreads();  // prior MFMA reads of As/Bs complete
#pragma unroll
    for (int i = 0; i < 2; i++) {
      gld_lds16(&Ap[(size_t)(rowA + i * 16) * 1024 + k0 + cch],
                &As[(w * 32 + i * 16) * 32]);
      gld_lds16(&Bp[(size_t)(rowB + i * 16) * 1024 + k0 + cch],
                &Bs[(w * 32 + i * 16) * 32]);
    }
    __syncthreads();  // drains vmcnt (compiler-inserted) -> tiles ready

    bf16x8 af[4], bfr[4];
#pragma unroll
    for (int t = 0; t < 4; t++) {
      af[t]  = *(const bf16x8*)&As[(wm * 64 + t * 16 + m16) * 32 + quad * 8];
      bfr[t] = *(const bf16x8*)&Bs[(wn * 64 + t * 16 + m16) * 32 + quad * 8];
    }
#pragma unroll
    for (int mt = 0; mt < 4; mt++)
#pragma unroll
      for (int nt = 0; nt < 4; nt++)
        acc[mt][nt] = __builtin_amdgcn_mfma_f32_16x16x32_bf16(
            af[mt], bfr[nt], acc[mt][nt], 0, 0, 0);
  }

  // Epilogue. C/D layout: col(n)=lane&15, row(m)=quad*4+reg.
  if (which < 2) {
    u16* __restrict__ out = which == 0 ? qo : ko;
#pragma unroll
    for (int mt = 0; mt < 4; mt++) {
      const int row = m0 + wm * 64 + mt * 16 + quad * 4;
#pragma unroll
      for (int nt = 0; nt < 4; nt++) {
        const int n = n0 + wn * 64 + nt * 16 + m16;
        f32x4 a = acc[mt][nt];
#pragma unroll
        for (int r = 0; r < 4; r++)
          out[(size_t)(row + r) * 1024 + n] = f2bf(a[r]);
      }
    }
  } else {
#pragma unroll
    for (int mt = 0; mt < 4; mt++) {
      const int row = m0 + wm * 64 + mt * 16 + quad * 4;  // d index
#pragma unroll
      for (int nt = 0; nt < 4; nt++) {
        const int n = n0 + wn * 64 + nt * 16 + m16;       // x row
        f32x4 a = acc[mt][nt];
#pragma unroll
        for (int r = 0; r < 4; r++)
          vt[(size_t)(row + r) * 4096 + n] = f2bf(a[r]);
      }
    }
  }
}

// ---------------------------------------------------------------------------
// Kernel 2: standalone RoPE, in-place on q/k.
// ---------------------------------------------------------------------------
__global__ __launch_bounds__(256) void rope_inplace(u16* __restrict__ qb,
                                                    u16* __restrict__ kb) {
  u16* buf = blockIdx.y == 0 ? qb : kb;
  const int p = blockIdx.x * 256 + (int)threadIdx.x;
  const int nidx = p * 2;
  const int row = nidx >> 10;
  const int col = nidx & 1023;
  const int i = (col & 63) >> 1;
  const int t = row & 2047;
  const float theta = exp2f(-(float)i * 0.02595256324130752f);
  const float ang = (float)t * theta;
  float s, c;
  sincosf(ang, &s, &c);
  const float a0 = bf2f(buf[(size_t)row * 1024 + col]);
  const float a1 = bf2f(buf[(size_t)row * 1024 + col + 1]);
  buf[(size_t)row * 1024 + col]     = f2bf(a0 * c - a1 * s);
  buf[(size_t)row * 1024 + col + 1] = f2bf(a1 * c + a0 * s);
}

// ---------------------------------------------------------------------------
// Kernel 3: causal flash attention, NO-RESCALE softmax, in-register P (T12),
// KVBLK=128 (2 K-tiles per barrier round: halves per-round overhead, which
// profiling showed dominates: ~3800 cy/tile vs <700 cy pipe work), l computed
// via MFMA against an all-ones B fragment (l = sum_k P[k][q] lands already
// indexed by the O-store row r; still summed from the ROUNDED bf16 P so
// rounding cancels in O/l; kills the extraction bit-ops and the shuffle
// reduction). XCD-aware block swizzle: each XCD's 64 resident blocks cover 4
// heads -> K/V working set 2MB < 4MB L2 (was 16MB -> 117MB HBM refetch).
// Pair-balanced (qt = x then 31-x => 17 rounds per block), reg-prefetch K/V.
// ---------------------------------------------------------------------------
__global__ __launch_bounds__(256) void flash_attn(
    const u16* __restrict__ qg, const u16* __restrict__ kg,
    const u16* __restrict__ vt, float* __restrict__ out) {
  __shared__ __align__(16) u16 Qs[64 * 72];
  __shared__ __align__(16) u16 Ks[128 * 72];   // [key][d]
  __shared__ __align__(16) u16 Vs[64 * 136];   // [d][kperm], kperm=swap23(key)

  const int tid = threadIdx.x, lane = tid & 63, w = tid >> 6;
  const int quad = lane >> 4, m16 = lane & 15;

  // XCD swizzle: 512 blocks, HW round-robins linear id across 8 XCDs.
  // wid = (id%8)*64 + id/8 gives each XCD 64 consecutive wids = 4 heads.
  const int id  = (int)blockIdx.x;
  const int wid = (id & 7) * 64 + (id >> 3);
  const int xq  = wid & 15;         // q-tile pair index
  const int h   = (wid >> 4) & 15;  // head
  const int b   = wid >> 8;         // batch

  const size_t base = (size_t)b * 2048 * 1024 + (size_t)h * 64;
  const size_t vbase = (size_t)(h * 64) * 4096 + (size_t)b * 2048;
  const float SC = 0.03125f * LOG2E;

  const f32x4 z4 = {0.f, 0.f, 0.f, 0.f};
  const int srow = tid >> 2, sc = (tid & 3) * 16;

  union { u16x8 u; bf16x8 f; } ones;
#pragma unroll
  for (int j = 0; j < 8; j++) ones.u[j] = 0x3F80;  // bf16 1.0

  for (int pass = 0; pass < 2; ++pass) {
    const int qt = pass == 0 ? xq : 31 - xq;
    const int q0 = qt * 64;
    const int nr = (qt + 2) >> 1;  // rounds of 128 keys

    __syncthreads();  // prior pass's LDS reads complete
    {
      const u16* src = &qg[base + (size_t)(q0 + srow) * 1024 + sc];
      *(u16x8*)&Qs[srow * 72 + sc] = *(const u16x8*)src;
      *(u16x8*)&Qs[srow * 72 + sc + 8] = *(const u16x8*)(src + 8);
    }
    u16x8 kr0, kr1, kr2, kr3, vr0, vr1, vr2, vr3;
    {
      const u16* ks = &kg[base + (size_t)srow * 1024 + sc];
      kr0 = *(const u16x8*)ks; kr1 = *(const u16x8*)(ks + 8);
      const u16* ks2 = ks + (size_t)64 * 1024;
      kr2 = *(const u16x8*)ks2; kr3 = *(const u16x8*)(ks2 + 8);
      const u16* vs = &vt[vbase + (size_t)srow * 4096 + sc];
      vr0 = *(const u16x8*)vs; vr1 = *(const u16x8*)(vs + 8);
      vr2 = *(const u16x8*)(vs + 64); vr3 = *(const u16x8*)(vs + 72);
    }
    __syncthreads();
    const bf16x8 qf0 = *(const bf16x8*)&Qs[(w * 16 + m16) * 72 + quad * 8];
    const bf16x8 qf1 = *(const bf16x8*)&Qs[(w * 16 + m16) * 72 + 32 + quad * 8];

    f32x4 l4 = z4;  // l[r] = denom for q row qrow0+r (via ones-MFMA)
    f32x4 O[4];
#pragma unroll
    for (int d = 0; d < 4; d++) O[d] = z4;

    const int qrow0 = q0 + w * 16 + quad * 4;  // O store rows
    const int qcol  = q0 + w * 16 + m16;       // this lane's softmax q

    for (int rr = 0; rr < nr; ++rr) {
      const int k0 = rr * 128;
      if (rr) __syncthreads();  // all waves done with prev Ks/Vs
      *(u16x8*)&Ks[srow * 72 + sc] = kr0;
      *(u16x8*)&Ks[srow * 72 + sc + 8] = kr1;
      *(u16x8*)&Ks[(64 + srow) * 72 + sc] = kr2;
      *(u16x8*)&Ks[(64 + srow) * 72 + sc + 8] = kr3;
      {  // Vs store with key bit2<->bit3 swap within each 16-block
        const u16x4* v0 = (const u16x4*)&vr0;
        const u16x4* v1 = (const u16x4*)&vr1;
        *(u16x4*)&Vs[srow * 136 + sc]      = v0[0];
        *(u16x4*)&Vs[srow * 136 + sc + 4]  = v1[0];
        *(u16x4*)&Vs[srow * 136 + sc + 8]  = v0[1];
        *(u16x4*)&Vs[srow * 136 + sc + 12] = v1[1];
        const u16x4* v2 = (const u16x4*)&vr2;
        const u16x4* v3 = (const u16x4*)&vr3;
        *(u16x4*)&Vs[srow * 136 + 64 + sc]      = v2[0];
        *(u16x4*)&Vs[srow * 136 + 64 + sc + 4]  = v3[0];
        *(u16x4*)&Vs[srow * 136 + 64 + sc + 8]  = v2[1];
        *(u16x4*)&Vs[srow * 136 + 64 + sc + 12] = v3[1];
      }
      __syncthreads();
      if (rr + 1 < nr) {  // prefetch next round; overlaps MFMA + softmax
        const u16* ks = &kg[base + (size_t)(k0 + 128 + srow) * 1024 + sc];
        kr0 = *(const u16x8*)ks; kr1 = *(const u16x8*)(ks + 8);
        const u16* ks2 = ks + (size_t)64 * 1024;
        kr2 = *(const u16x8*)ks2; kr3 = *(const u16x8*)(ks2 + 8);
        const u16* vs = &vt[vbase + (size_t)srow * 4096 + k0 + 128 + sc];
        vr0 = *(const u16x8*)vs; vr1 = *(const u16x8*)(vs + 8);
        vr2 = *(const u16x8*)(vs + 64); vr3 = *(const u16x8*)(vs + 72);
      }

      // S^T = K Q^T over 128 keys: S[nt] rows = key nt*16+quad*4+r, col=q
      f32x4 S[8];
#pragma unroll
      for (int nt = 0; nt < 8; nt++) {
        const bf16x8 kf0 = *(const bf16x8*)&Ks[(nt * 16 + m16) * 72 + quad * 8];
        const bf16x8 kf1 =
            *(const bf16x8*)&Ks[(nt * 16 + m16) * 72 + 32 + quad * 8];
        S[nt] = __builtin_amdgcn_mfma_f32_16x16x32_bf16(kf0, qf0, z4, 0, 0, 0);
        S[nt] = __builtin_amdgcn_mfma_f32_16x16x32_bf16(kf1, qf1, S[nt], 0, 0, 0);
      }

      // p = exp2(s*SC); mask only on the last round (covers diag + dead half)
      const bool lastr = (rr == nr - 1);
      uint32_t W[16];
#pragma unroll
      for (int nt = 0; nt < 8; nt++) {
        float p[4];
#pragma unroll
        for (int r = 0; r < 4; r++) {
          float e = exp2f(S[nt][r] * SC);
          const int key = k0 + nt * 16 + quad * 4 + r;
          if (lastr && key > qcol) e = 0.f;
          p[r] = e;
        }
        uint32_t w0, w1;
        asm("v_cvt_pk_bf16_f32 %0, %1, %2" : "=v"(w0) : "v"(p[0]), "v"(p[1]));
        asm("v_cvt_pk_bf16_f32 %0, %1, %2" : "=v"(w1) : "v"(p[2]), "v"(p[3]));
        W[2 * nt] = w0; W[2 * nt + 1] = w1;
      }

      // Assemble PV A-frags: one permlane32_swap pair per 32-key block.
      union { u32v4 u; bf16x8 f; } P[4];
#pragma unroll
      for (int ks = 0; ks < 4; ks++) {
        uint32_t a0 = W[4 * ks], b0 = W[4 * ks + 2];
        uint32_t a1 = W[4 * ks + 1], b1 = W[4 * ks + 3];
        asm("v_permlane32_swap_b32 %0, %1" : "+v"(a0), "+v"(b0));
        asm("v_permlane32_swap_b32 %0, %1" : "+v"(a1), "+v"(b1));
        P[ks].u = (u32v4){a0, a1, b0, b1};
      }

      // l += P * ones  (row sums of rounded P; same row indexing as O)
#pragma unroll
      for (int ks = 0; ks < 4; ks++)
        l4 = __builtin_amdgcn_mfma_f32_16x16x32_bf16(P[ks].f, ones.f, l4,
                                                     0, 0, 0);

      // O += P V  (Vs already key-permuted to match the frag order)
#pragma unroll
      for (int dt = 0; dt < 4; dt++) {
#pragma unroll
        for (int ks = 0; ks < 4; ks++) {
          const bf16x8 vf =
              *(const bf16x8*)&Vs[(dt * 16 + m16) * 136 + ks * 32 + quad * 8];
          O[dt] = __builtin_amdgcn_mfma_f32_16x16x32_bf16(P[ks].f, vf, O[dt],
                                                          0, 0, 0);
        }
      }
    }

    float inv[4];
#pragma unroll
    for (int r = 0; r < 4; r++) inv[r] = 1.0f / l4[r];

#pragma unroll
    for (int dt = 0; dt < 4; dt++)
#pragma unroll
      for (int r = 0; r < 4; r++)
        out[base + (size_t)(qrow0 + r) * 1024 + dt * 16 + m16] =
            O[dt][r] * inv[r];
  }
}

extern "C" void kernel_launch(void* const* d_in, const int* in_sizes, int n_in,
                              void* d_out, int out_size, void* d_ws, size_t ws_size,
                              hipStream_t stream) {
  const float* x  = (const float*)d_in[0];
  const float* Wq = (const float*)d_in[1];
  const float* Wk = (const float*)d_in[2];
  const float* Wv = (const float*)d_in[3];
  u16* qb  = (u16*)d_ws;                    // [4096][1024] bf16
  u16* kb  = qb  + (size_t)4096 * 1024;     // [4096][1024] bf16
  u16* vtw = kb  + (size_t)4096 * 1024;     // [1024][4096] bf16 (V^T)
  u16* xc  = vtw + (size_t)4096 * 1024;     // bf16 inputs
  u16* wqc = xc  + (size_t)4096 * 1024;
  u16* wkc = wqc + (size_t)1024 * 1024;
  u16* wvc = wkc + (size_t)1024 * 1024;

  f32_to_bf16<<<dim3(2048, 4), 256, 0, stream>>>(x, Wq, Wk, Wv,
                                                 xc, wqc, wkc, wvc);
  qkv_gemm<<<dim3(8, 32, 3), 256, 0, stream>>>(xc, wqc, wkc, wvc,
                                               qb, kb, vtw);
  rope_inplace<<<dim3(8192, 2), 256, 0, stream>>>(qb, kb);
  flash_attn<<<dim3(512, 1, 1), 256, 0, stream>>>(qb, kb, vtw, (float*)d_out);
}

// Round 3
// 165.814 us; speedup vs baseline: 1.0264x; 1.0058x over previous
//
#include <hip/hip_runtime.h>
#include <stdint.h>

typedef unsigned short u16;
typedef __bf16 bf16x8 __attribute__((ext_vector_type(8)));
typedef unsigned short u16x8 __attribute__((ext_vector_type(8)));
typedef unsigned short u16x4 __attribute__((ext_vector_type(4)));
typedef float f32x4 __attribute__((ext_vector_type(4)));
typedef uint32_t u32v4 __attribute__((ext_vector_type(4)));

#define LOG2E 1.4426950408889634f

typedef const __attribute__((address_space(1))) uint32_t as1_u32;
typedef __attribute__((address_space(3))) uint32_t as3_u32;

// float -> bf16 round-to-nearest-even
__device__ __forceinline__ u16 f2bf(float f) {
  union { float f; uint32_t i; } v; v.f = f;
  uint32_t r = (v.i + 0x7fffu + ((v.i >> 16) & 1u)) >> 16;
  return (u16)r;
}
__device__ __forceinline__ float bf2f(u16 u) {
  union { uint32_t i; float f; } v; v.i = ((uint32_t)u) << 16; return v.f;
}

// async global->LDS, 16B/lane. LDS dest = wave-uniform base; HW scatters
// lane i to base + i*16B (matches As/Bs row layout: row stride 64B).
__device__ __forceinline__ void gld_lds16(const void* g, void* l) {
  as1_u32* gp = (as1_u32*)((uintptr_t)g);
  as3_u32* lp = (as3_u32*)(uint32_t)(uintptr_t)(l);
  __builtin_amdgcn_global_load_lds(gp, lp, 16, 0, 0);
}

// ---------------------------------------------------------------------------
// Kernel 0: f32 -> bf16 convert.
// ---------------------------------------------------------------------------
__global__ __launch_bounds__(256) void f32_to_bf16(
    const float* __restrict__ x, const float* __restrict__ wq,
    const float* __restrict__ wk, const float* __restrict__ wv,
    u16* __restrict__ xc, u16* __restrict__ wqc,
    u16* __restrict__ wkc, u16* __restrict__ wvc) {
  const int z = blockIdx.y;
  const float* src = z == 0 ? x : (z == 1 ? wq : (z == 2 ? wk : wv));
  u16* dst = z == 0 ? xc : (z == 1 ? wqc : (z == 2 ? wkc : wvc));
  const int n = z == 0 ? (1 << 22) : (1 << 20);

  const int idx = (blockIdx.x * 256 + (int)threadIdx.x) * 8;
  if (idx >= n) return;
  const f32x4 a = *(const f32x4*)&src[idx];
  const f32x4 b = *(const f32x4*)&src[idx + 4];
  u16x8 o;
#pragma unroll
  for (int j = 0; j < 4; j++) { o[j] = f2bf(a[j]); o[j + 4] = f2bf(b[j]); }
  *(u16x8*)&dst[idx] = o;
}

// ---------------------------------------------------------------------------
// Kernel 1: QKV GEMM, 128x128 tile, BK=32, m97-style global_load_lds staging.
//  z=0/1: q/k = x @ W^T -> [4096][1024]
//  z=2  : vt = Wv @ x^T -> [1024][4096] (coalesced store)
// ---------------------------------------------------------------------------
__global__ __launch_bounds__(256) void qkv_gemm(
    const u16* __restrict__ xc, const u16* __restrict__ wqc,
    const u16* __restrict__ wkc, const u16* __restrict__ wvc,
    u16* __restrict__ qo, u16* __restrict__ ko, u16* __restrict__ vt) {
  __shared__ __align__(16) u16 As[128 * 32];
  __shared__ __align__(16) u16 Bs[128 * 32];

  const int tid = threadIdx.x;
  const int lane = tid & 63;
  const int w = tid >> 6;
  const int wm = w >> 1, wn = w & 1;
  const int quad = lane >> 4, m16 = lane & 15;
  const int which = blockIdx.z;

  const u16* __restrict__ Ap;
  const u16* __restrict__ Bp;
  int m0, n0;
  if (which == 2) {
    Ap = wvc; Bp = xc;
    m0 = blockIdx.x * 128;   // Wv rows (1024)
    n0 = blockIdx.y * 128;   // x rows (4096)
  } else {
    Ap = xc; Bp = which == 0 ? wqc : wkc;
    m0 = blockIdx.y * 128;   // x rows
    n0 = blockIdx.x * 128;   // W rows
  }

  const f32x4 z4 = {0.f, 0.f, 0.f, 0.f};
  f32x4 acc[4][4];
#pragma unroll
  for (int i = 0; i < 4; i++)
#pragma unroll
    for (int j = 0; j < 4; j++) acc[i][j] = z4;

  const int rowA = m0 + w * 32 + (lane >> 2);
  const int rowB = n0 + w * 32 + (lane >> 2);
  const int cch = (lane & 3) * 8;

  for (int k0 = 0; k0 < 1024; k0 += 32) {
    __syncthreads();  // prior MFMA reads of As/Bs complete
#pragma unroll
    for (int i = 0; i < 2; i++) {
      gld_lds16(&Ap[(size_t)(rowA + i * 16) * 1024 + k0 + cch],
                &As[(w * 32 + i * 16) * 32]);
      gld_lds16(&Bp[(size_t)(rowB + i * 16) * 1024 + k0 + cch],
                &Bs[(w * 32 + i * 16) * 32]);
    }
    __syncthreads();  // drains vmcnt (compiler-inserted) -> tiles ready

    bf16x8 af[4], bfr[4];
#pragma unroll
    for (int t = 0; t < 4; t++) {
      af[t]  = *(const bf16x8*)&As[(wm * 64 + t * 16 + m16) * 32 + quad * 8];
      bfr[t] = *(const bf16x8*)&Bs[(wn * 64 + t * 16 + m16) * 32 + quad * 8];
    }
#pragma unroll
    for (int mt = 0; mt < 4; mt++)
#pragma unroll
      for (int nt = 0; nt < 4; nt++)
        acc[mt][nt] = __builtin_amdgcn_mfma_f32_16x16x32_bf16(
            af[mt], bfr[nt], acc[mt][nt], 0, 0, 0);
  }

  // Epilogue. C/D layout: col(n)=lane&15, row(m)=quad*4+reg.
  if (which < 2) {
    u16* __restrict__ out = which == 0 ? qo : ko;
#pragma unroll
    for (int mt = 0; mt < 4; mt++) {
      const int row = m0 + wm * 64 + mt * 16 + quad * 4;
#pragma unroll
      for (int nt = 0; nt < 4; nt++) {
        const int n = n0 + wn * 64 + nt * 16 + m16;
        f32x4 a = acc[mt][nt];
#pragma unroll
        for (int r = 0; r < 4; r++)
          out[(size_t)(row + r) * 1024 + n] = f2bf(a[r]);
      }
    }
  } else {
#pragma unroll
    for (int mt = 0; mt < 4; mt++) {
      const int row = m0 + wm * 64 + mt * 16 + quad * 4;  // d index
#pragma unroll
      for (int nt = 0; nt < 4; nt++) {
        const int n = n0 + wn * 64 + nt * 16 + m16;       // x row
        f32x4 a = acc[mt][nt];
#pragma unroll
        for (int r = 0; r < 4; r++)
          vt[(size_t)(row + r) * 4096 + n] = f2bf(a[r]);
      }
    }
  }
}

// ---------------------------------------------------------------------------
// Kernel 2: standalone RoPE, in-place on q/k.
// ---------------------------------------------------------------------------
__global__ __launch_bounds__(256) void rope_inplace(u16* __restrict__ qb,
                                                    u16* __restrict__ kb) {
  u16* buf = blockIdx.y == 0 ? qb : kb;
  const int p = blockIdx.x * 256 + (int)threadIdx.x;
  const int nidx = p * 2;
  const int row = nidx >> 10;
  const int col = nidx & 1023;
  const int i = (col & 63) >> 1;
  const int t = row & 2047;
  const float theta = exp2f(-(float)i * 0.02595256324130752f);
  const float ang = (float)t * theta;
  float s, c;
  sincosf(ang, &s, &c);
  const float a0 = bf2f(buf[(size_t)row * 1024 + col]);
  const float a1 = bf2f(buf[(size_t)row * 1024 + col + 1]);
  buf[(size_t)row * 1024 + col]     = f2bf(a0 * c - a1 * s);
  buf[(size_t)row * 1024 + col + 1] = f2bf(a1 * c + a0 * s);
}

// ---------------------------------------------------------------------------
// Kernel 3: causal flash attention. Round-2 lesson: FETCH dropped 117->12MB
// with zero time change -> latency/occupancy-bound (2 blocks/CU). This round:
// one q-tile per block (grid 1024), Qs LDS dropped (Q frags direct from
// global to regs) -> LDS 35840B -> 4 blocks/CU; __launch_bounds__(256,4)
// caps VGPR at 128 for 16 waves/CU. qt chosen so each CU's 4 resident
// blocks are {qt, 31-qt, qt, 31-qt} (34 rounds, balanced), and each XCD
// still sees only 4 heads (2MB K+V < 4MB L2; keeps round-2's FETCH win).
// In-register P (T12), KVBLK=128, l via ones-MFMA, reg-prefetch K/V.
// ---------------------------------------------------------------------------
__global__ __launch_bounds__(256, 4) void flash_attn(
    const u16* __restrict__ qg, const u16* __restrict__ kg,
    const u16* __restrict__ vt, float* __restrict__ out) {
  __shared__ __align__(16) u16 Ks[128 * 72];   // [key][d]
  __shared__ __align__(16) u16 Vs[64 * 136];   // [d][kperm], kperm=swap23(key)

  const int tid = threadIdx.x, lane = tid & 63, w = tid >> 6;
  const int quad = lane >> 4, m16 = lane & 15;

  // XCD swizzle (id%8 = XCD) + per-CU balance: slots differ in v=wid>>5
  // parity -> qt alternates u / 31-u across a CU's resident blocks.
  const int id  = (int)blockIdx.x;
  const int wid = (id & 7) * 128 + (id >> 3);
  const int uu  = wid & 31;
  const int v   = wid >> 5;          // (h,b) combo, 0..31
  const int qt  = (v & 1) ? (31 - uu) : uu;
  const int h   = v & 15;
  const int b   = v >> 4;

  const size_t base = (size_t)b * 2048 * 1024 + (size_t)h * 64;
  const size_t vbase = (size_t)(h * 64) * 4096 + (size_t)b * 2048;
  const float SC = 0.03125f * LOG2E;

  const f32x4 z4 = {0.f, 0.f, 0.f, 0.f};
  const int srow = tid >> 2, sc = (tid & 3) * 16;

  union { u16x8 u; bf16x8 f; } ones;
#pragma unroll
  for (int j = 0; j < 8; j++) ones.u[j] = 0x3F80;  // bf16 1.0

  const int q0 = qt * 64;
  const int nr = (qt + 2) >> 1;  // rounds of 128 keys

  // Q fragments straight from global (L2-hit; once per block). Lane
  // (m16,quad) needs Q[q0+w*16+m16][quad*8..+8] and [32+quad*8..+8].
  const u16* qsrc = &qg[base + (size_t)(q0 + w * 16 + m16) * 1024 + quad * 8];
  const bf16x8 qf0 = *(const bf16x8*)qsrc;
  const bf16x8 qf1 = *(const bf16x8*)(qsrc + 32);

  // Prefetch round 0 K/V into regs.
  u16x8 kr0, kr1, kr2, kr3, vr0, vr1, vr2, vr3;
  {
    const u16* ks = &kg[base + (size_t)srow * 1024 + sc];
    kr0 = *(const u16x8*)ks; kr1 = *(const u16x8*)(ks + 8);
    const u16* ks2 = ks + (size_t)64 * 1024;
    kr2 = *(const u16x8*)ks2; kr3 = *(const u16x8*)(ks2 + 8);
    const u16* vs = &vt[vbase + (size_t)srow * 4096 + sc];
    vr0 = *(const u16x8*)vs; vr1 = *(const u16x8*)(vs + 8);
    vr2 = *(const u16x8*)(vs + 64); vr3 = *(const u16x8*)(vs + 72);
  }

  f32x4 l4 = z4;  // l[r] = denom for q row qrow0+r (via ones-MFMA)
  f32x4 O[4];
#pragma unroll
  for (int d = 0; d < 4; d++) O[d] = z4;

  const int qrow0 = q0 + w * 16 + quad * 4;  // O store rows
  const int qcol  = q0 + w * 16 + m16;       // this lane's softmax q

  for (int rr = 0; rr < nr; ++rr) {
    const int k0 = rr * 128;
    if (rr) __syncthreads();  // all waves done with prev Ks/Vs
    *(u16x8*)&Ks[srow * 72 + sc] = kr0;
    *(u16x8*)&Ks[srow * 72 + sc + 8] = kr1;
    *(u16x8*)&Ks[(64 + srow) * 72 + sc] = kr2;
    *(u16x8*)&Ks[(64 + srow) * 72 + sc + 8] = kr3;
    {  // Vs store with key bit2<->bit3 swap within each 16-block
      const u16x4* v0 = (const u16x4*)&vr0;
      const u16x4* v1 = (const u16x4*)&vr1;
      *(u16x4*)&Vs[srow * 136 + sc]      = v0[0];
      *(u16x4*)&Vs[srow * 136 + sc + 4]  = v1[0];
      *(u16x4*)&Vs[srow * 136 + sc + 8]  = v0[1];
      *(u16x4*)&Vs[srow * 136 + sc + 12] = v1[1];
      const u16x4* v2 = (const u16x4*)&vr2;
      const u16x4* v3 = (const u16x4*)&vr3;
      *(u16x4*)&Vs[srow * 136 + 64 + sc]      = v2[0];
      *(u16x4*)&Vs[srow * 136 + 64 + sc + 4]  = v3[0];
      *(u16x4*)&Vs[srow * 136 + 64 + sc + 8]  = v2[1];
      *(u16x4*)&Vs[srow * 136 + 64 + sc + 12] = v3[1];
    }
    __syncthreads();
    if (rr + 1 < nr) {  // prefetch next round; overlaps MFMA + softmax
      const u16* ks = &kg[base + (size_t)(k0 + 128 + srow) * 1024 + sc];
      kr0 = *(const u16x8*)ks; kr1 = *(const u16x8*)(ks + 8);
      const u16* ks2 = ks + (size_t)64 * 1024;
      kr2 = *(const u16x8*)ks2; kr3 = *(const u16x8*)(ks2 + 8);
      const u16* vs = &vt[vbase + (size_t)srow * 4096 + k0 + 128 + sc];
      vr0 = *(const u16x8*)vs; vr1 = *(const u16x8*)(vs + 8);
      vr2 = *(const u16x8*)(vs + 64); vr3 = *(const u16x8*)(vs + 72);
    }

    // S^T = K Q^T over 128 keys: S[nt] rows = key nt*16+quad*4+r, col=q
    f32x4 S[8];
#pragma unroll
    for (int nt = 0; nt < 8; nt++) {
      const bf16x8 kf0 = *(const bf16x8*)&Ks[(nt * 16 + m16) * 72 + quad * 8];
      const bf16x8 kf1 =
          *(const bf16x8*)&Ks[(nt * 16 + m16) * 72 + 32 + quad * 8];
      S[nt] = __builtin_amdgcn_mfma_f32_16x16x32_bf16(kf0, qf0, z4, 0, 0, 0);
      S[nt] = __builtin_amdgcn_mfma_f32_16x16x32_bf16(kf1, qf1, S[nt], 0, 0, 0);
    }

    // p = exp2(s*SC); mask only on the last round (covers diag + dead half)
    const bool lastr = (rr == nr - 1);
    uint32_t W[16];
#pragma unroll
    for (int nt = 0; nt < 8; nt++) {
      float p[4];
#pragma unroll
      for (int r = 0; r < 4; r++) {
        float e = exp2f(S[nt][r] * SC);
        const int key = k0 + nt * 16 + quad * 4 + r;
        if (lastr && key > qcol) e = 0.f;
        p[r] = e;
      }
      uint32_t w0, w1;
      asm("v_cvt_pk_bf16_f32 %0, %1, %2" : "=v"(w0) : "v"(p[0]), "v"(p[1]));
      asm("v_cvt_pk_bf16_f32 %0, %1, %2" : "=v"(w1) : "v"(p[2]), "v"(p[3]));
      W[2 * nt] = w0; W[2 * nt + 1] = w1;
    }

    // Assemble PV A-frags: one permlane32_swap pair per 32-key block.
    union { u32v4 u; bf16x8 f; } P[4];
#pragma unroll
    for (int ks = 0; ks < 4; ks++) {
      uint32_t a0 = W[4 * ks], b0 = W[4 * ks + 2];
      uint32_t a1 = W[4 * ks + 1], b1 = W[4 * ks + 3];
      asm("v_permlane32_swap_b32 %0, %1" : "+v"(a0), "+v"(b0));
      asm("v_permlane32_swap_b32 %0, %1" : "+v"(a1), "+v"(b1));
      P[ks].u = (u32v4){a0, a1, b0, b1};
    }

    // l += P * ones  (row sums of rounded P; same row indexing as O)
#pragma unroll
    for (int ks = 0; ks < 4; ks++)
      l4 = __builtin_amdgcn_mfma_f32_16x16x32_bf16(P[ks].f, ones.f, l4,
                                                   0, 0, 0);

    // O += P V  (Vs already key-permuted to match the frag order)
#pragma unroll
    for (int dt = 0; dt < 4; dt++) {
#pragma unroll
      for (int ks = 0; ks < 4; ks++) {
        const bf16x8 vf =
            *(const bf16x8*)&Vs[(dt * 16 + m16) * 136 + ks * 32 + quad * 8];
        O[dt] = __builtin_amdgcn_mfma_f32_16x16x32_bf16(P[ks].f, vf, O[dt],
                                                        0, 0, 0);
      }
    }
  }

  float inv[4];
#pragma unroll
  for (int r = 0; r < 4; r++) inv[r] = 1.0f / l4[r];

#pragma unroll
  for (int dt = 0; dt < 4; dt++)
#pragma unroll
    for (int r = 0; r < 4; r++)
      out[base + (size_t)(qrow0 + r) * 1024 + dt * 16 + m16] =
          O[dt][r] * inv[r];
}

extern "C" void kernel_launch(void* const* d_in, const int* in_sizes, int n_in,
                              void* d_out, int out_size, void* d_ws, size_t ws_size,
                              hipStream_t stream) {
  const float* x  = (const float*)d_in[0];
  const float* Wq = (const float*)d_in[1];
  const float* Wk = (const float*)d_in[2];
  const float* Wv = (const float*)d_in[3];
  u16* qb  = (u16*)d_ws;                    // [4096][1024] bf16
  u16* kb  = qb  + (size_t)4096 * 1024;     // [4096][1024] bf16
  u16* vtw = kb  + (size_t)4096 * 1024;     // [1024][4096] bf16 (V^T)
  u16* xc  = vtw + (size_t)4096 * 1024;     // bf16 inputs
  u16* wqc = xc  + (size_t)4096 * 1024;
  u16* wkc = wqc + (size_t)1024 * 1024;
  u16* wvc = wkc + (size_t)1024 * 1024;

  f32_to_bf16<<<dim3(2048, 4), 256, 0, stream>>>(x, Wq, Wk, Wv,
                                                 xc, wqc, wkc, wvc);
  qkv_gemm<<<dim3(8, 32, 3), 256, 0, stream>>>(xc, wqc, wkc, wvc,
                                               qb, kb, vtw);
  rope_inplace<<<dim3(8192, 2), 256, 0, stream>>>(qb, kb);
  flash_attn<<<dim3(1024, 1, 1), 256, 0, stream>>>(qb, kb, vtw, (float*)d_out);
}